// Round 1
// baseline (55.046 us; speedup 1.0000x reference)
//
#include <hip/hip_runtime.h>

// RBF kernel matrix: out[r,i,j] = os^2 * exp(-0.5 * sum_d ((x1[r,i,d]-x2[r,j,d])/ls[d])^2)
// R=4, N1=N2=4096, D=8. Output 268 MB fp32 -> write-BW bound (~43 us floor at 6.3 TB/s).

constexpr int D  = 8;
constexpr int BI = 64;   // i-tile (x1 rows) per block
constexpr int BJ = 64;   // j-tile (x2 rows) per block

__global__ __launch_bounds__(256, 4) void rbf_kernel(
    const float* __restrict__ x1, const float* __restrict__ x2,
    const float* __restrict__ ls, const float* __restrict__ osc,
    float* __restrict__ out, int N1, int N2)
{
    __shared__ float sa[BI][D];   // x1 tile, pre-scaled by 1/ls, point-major
    __shared__ float sb[D][BJ];   // x2 tile, pre-scaled, d-major (conflict-free b128 reads)

    const int r   = blockIdx.z;
    const int i0  = blockIdx.y * BI;
    const int j0  = blockIdx.x * BJ;
    const int tid = threadIdx.x;

    // ---- cooperative stage: threads 0..127 -> x1 tile, 128..255 -> x2 tile ----
    // each staging thread moves one float4 (half a point)
    const int t  = tid & 127;
    const int pt = t >> 1;        // point within tile [0,64)
    const int hf = t & 1;         // which half of the 8 dims

    float4 lsv = *reinterpret_cast<const float4*>(ls + hf * 4);
    float4 inv;
    inv.x = 1.0f / lsv.x; inv.y = 1.0f / lsv.y;
    inv.z = 1.0f / lsv.z; inv.w = 1.0f / lsv.w;

    if (tid < 128) {
        const float* src = x1 + ((size_t)r * N1 + (i0 + pt)) * D + hf * 4;
        float4 v = *reinterpret_cast<const float4*>(src);
        v.x *= inv.x; v.y *= inv.y; v.z *= inv.z; v.w *= inv.w;
        *reinterpret_cast<float4*>(&sa[pt][hf * 4]) = v;
    } else {
        const float* src = x2 + ((size_t)r * N2 + (j0 + pt)) * D + hf * 4;
        float4 v = *reinterpret_cast<const float4*>(src);
        v.x *= inv.x; v.y *= inv.y; v.z *= inv.z; v.w *= inv.w;
        sb[hf * 4 + 0][pt] = v.x;   // transpose into d-major (2-way conflict, free)
        sb[hf * 4 + 1][pt] = v.y;
        sb[hf * 4 + 2][pt] = v.z;
        sb[hf * 4 + 3][pt] = v.w;
    }
    const float os2 = osc[0] * osc[0];
    __syncthreads();

    // ---- per-thread 4(i) x 4(j) register tile ----
    const int tx = tid & 15;   // j-group: 4 consecutive j per thread -> float4 store
    const int ty = tid >> 4;   // i-group: 4 i rows per thread

    float4 b[D];               // the 4 j-points, one float4 (over j) per dim
#pragma unroll
    for (int d = 0; d < D; ++d)
        b[d] = *reinterpret_cast<const float4*>(&sb[d][tx * 4]);

    float a[4][D];             // the 4 i-points
#pragma unroll
    for (int ii = 0; ii < 4; ++ii) {
#pragma unroll
        for (int h = 0; h < 2; ++h) {
            float4 v = *reinterpret_cast<const float4*>(&sa[ty * 4 + ii][h * 4]);
            a[ii][h * 4 + 0] = v.x; a[ii][h * 4 + 1] = v.y;
            a[ii][h * 4 + 2] = v.z; a[ii][h * 4 + 3] = v.w;
        }
    }

#pragma unroll
    for (int ii = 0; ii < 4; ++ii) {
        float s0 = 0.f, s1 = 0.f, s2 = 0.f, s3 = 0.f;
#pragma unroll
        for (int d = 0; d < D; ++d) {
            const float  av = a[ii][d];
            const float4 bv = b[d];
            const float d0 = av - bv.x, d1 = av - bv.y;
            const float d2 = av - bv.z, d3 = av - bv.w;
            s0 = fmaf(d0, d0, s0); s1 = fmaf(d1, d1, s1);
            s2 = fmaf(d2, d2, s2); s3 = fmaf(d3, d3, s3);
        }
        float4 o;
        o.x = os2 * __expf(-0.5f * s0);
        o.y = os2 * __expf(-0.5f * s1);
        o.z = os2 * __expf(-0.5f * s2);
        o.w = os2 * __expf(-0.5f * s3);
        const int i = i0 + ty * 4 + ii;
        *reinterpret_cast<float4*>(out + ((size_t)r * N1 + i) * N2 + j0 + tx * 4) = o;
    }
}

extern "C" void kernel_launch(void* const* d_in, const int* in_sizes, int n_in,
                              void* d_out, int out_size, void* d_ws, size_t ws_size,
                              hipStream_t stream) {
    (void)in_sizes; (void)n_in; (void)d_ws; (void)ws_size; (void)out_size;
    const float* x1  = (const float*)d_in[0];
    const float* x2  = (const float*)d_in[1];
    const float* ls  = (const float*)d_in[2];
    const float* osc = (const float*)d_in[3];
    float* out = (float*)d_out;

    const int R = 4, N1 = 4096, N2 = 4096;
    dim3 grid(N2 / BJ, N1 / BI, R);
    rbf_kernel<<<grid, dim3(256), 0, stream>>>(x1, x2, ls, osc, out, N1, N2);
}

// Round 2
// 51.038 us; speedup vs baseline: 1.0785x; 1.0785x over previous
//
#include <hip/hip_runtime.h>

// RBF kernel matrix: out[r,i,j] = os^2 * exp(-0.5 * ||(x1_i - x2_j)/ls||^2)
// R=4, N1=N2=4096, D=8. Output 268 MB fp32 -> write-BW bound.
// Floor ~38 us at the 7.1 TB/s pure-write rate observed from fillBuffer.
// Design: BI=16 x BJ=256 tile; each wave stores 1 KB contiguous per row;
// Gram identity (asq + bb - 2 a.b) with LDS-staged norms; exp2-folded constants.

constexpr int D  = 8;
constexpr int BI = 16;    // x1 rows per block (4 per wave)
constexpr int BJ = 256;   // x2 cols per block (4 per lane)

#if __has_builtin(__builtin_amdgcn_exp2f)
#define FAST_EXP2(x) __builtin_amdgcn_exp2f(x)
#else
#define FAST_EXP2(x) __expf((x) * 0.69314718f)   // exp(x*ln2) == 2^x
#endif

__global__ __launch_bounds__(256, 6) void rbf_kernel(
    const float* __restrict__ x1, const float* __restrict__ x2,
    const float* __restrict__ ls, const float* __restrict__ osc,
    float* __restrict__ out, int N1, int N2)
{
    __shared__ float sb[D][BJ];   // x2 tile, scaled, d-major  (8 KB)
    __shared__ float sbb[BJ];     // ||b||^2 per j             (1 KB)
    __shared__ float sa[BI][D];   // x1 tile, scaled           (512 B)
    __shared__ float sasq[BI];    // ||a||^2 per i             (64 B)

    const int r   = blockIdx.z;
    const int i0  = blockIdx.y * BI;
    const int j0  = blockIdx.x * BJ;
    const int tid = threadIdx.x;

    float4 l0 = *reinterpret_cast<const float4*>(ls);
    float4 l1 = *reinterpret_cast<const float4*>(ls + 4);
    float4 inv0, inv1;
    inv0.x = 1.0f / l0.x; inv0.y = 1.0f / l0.y; inv0.z = 1.0f / l0.z; inv0.w = 1.0f / l0.w;
    inv1.x = 1.0f / l1.x; inv1.y = 1.0f / l1.y; inv1.z = 1.0f / l1.z; inv1.w = 1.0f / l1.w;

    // ---- stage x2: one point per thread (wave reads 2 KB contiguous) ----
    {
        const float* src = x2 + ((size_t)r * N2 + j0 + tid) * D;
        float4 v0 = *reinterpret_cast<const float4*>(src);
        float4 v1 = *reinterpret_cast<const float4*>(src + 4);
        v0.x *= inv0.x; v0.y *= inv0.y; v0.z *= inv0.z; v0.w *= inv0.w;
        v1.x *= inv1.x; v1.y *= inv1.y; v1.z *= inv1.z; v1.w *= inv1.w;
        sb[0][tid] = v0.x; sb[1][tid] = v0.y; sb[2][tid] = v0.z; sb[3][tid] = v0.w;
        sb[4][tid] = v1.x; sb[5][tid] = v1.y; sb[6][tid] = v1.z; sb[7][tid] = v1.w;
        sbb[tid] = v0.x*v0.x + v0.y*v0.y + v0.z*v0.z + v0.w*v0.w
                 + v1.x*v1.x + v1.y*v1.y + v1.z*v1.z + v1.w*v1.w;
    }
    // ---- stage x1: threads 0..15, one point each ----
    if (tid < BI) {
        const float* src = x1 + ((size_t)r * N1 + i0 + tid) * D;
        float4 v0 = *reinterpret_cast<const float4*>(src);
        float4 v1 = *reinterpret_cast<const float4*>(src + 4);
        v0.x *= inv0.x; v0.y *= inv0.y; v0.z *= inv0.z; v0.w *= inv0.w;
        v1.x *= inv1.x; v1.y *= inv1.y; v1.z *= inv1.z; v1.w *= inv1.w;
        *reinterpret_cast<float4*>(&sa[tid][0]) = v0;
        *reinterpret_cast<float4*>(&sa[tid][4]) = v1;
        sasq[tid] = v0.x*v0.x + v0.y*v0.y + v0.z*v0.z + v0.w*v0.w
                  + v1.x*v1.x + v1.y*v1.y + v1.z*v1.z + v1.w*v1.w;
    }
    const float os2 = osc[0] * osc[0];
    __syncthreads();

    // ---- compute: wave wv owns rows wv*4..wv*4+3; lane owns 4 consecutive j ----
    const int lane = tid & 63;
    const int wv   = tid >> 6;

    float4 bd[D];                 // b values for this lane's 4 j, per dim
#pragma unroll
    for (int d = 0; d < D; ++d)
        bd[d] = *reinterpret_cast<const float4*>(&sb[d][lane * 4]);
    const float4 bb4 = *reinterpret_cast<const float4*>(&sbb[lane * 4]);

    constexpr float L2E  = 1.44269504f;   //  log2(e)
    constexpr float NH2E = -0.72134752f;  // -0.5*log2(e)

    float* obase = out + ((size_t)r * N1 + i0) * (size_t)N2 + j0 + lane * 4;

#pragma unroll
    for (int ii = 0; ii < 4; ++ii) {
        const int row = wv * 4 + ii;
        // wave-broadcast LDS reads (same address all lanes -> free)
        const float4 a0  = *reinterpret_cast<const float4*>(&sa[row][0]);
        const float4 a1  = *reinterpret_cast<const float4*>(&sa[row][4]);
        const float  asq = sasq[row];

        float4 ch;   // -0.5*log2e*(asq + bb_j)
        ch.x = (asq + bb4.x) * NH2E;
        ch.y = (asq + bb4.y) * NH2E;
        ch.z = (asq + bb4.z) * NH2E;
        ch.w = (asq + bb4.w) * NH2E;

        float d0 = 0.f, d1 = 0.f, d2 = 0.f, d3 = 0.f;
        const float a[D] = {a0.x, a0.y, a0.z, a0.w, a1.x, a1.y, a1.z, a1.w};
#pragma unroll
        for (int d = 0; d < D; ++d) {
            const float av = a[d];
            d0 = fmaf(av, bd[d].x, d0);
            d1 = fmaf(av, bd[d].y, d1);
            d2 = fmaf(av, bd[d].z, d2);
            d3 = fmaf(av, bd[d].w, d3);
        }
        // exp(-0.5*s) = 2^( dot*log2e - 0.5*log2e*(asq+bb) )
        float4 o;
        o.x = os2 * FAST_EXP2(fmaf(d0, L2E, ch.x));
        o.y = os2 * FAST_EXP2(fmaf(d1, L2E, ch.y));
        o.z = os2 * FAST_EXP2(fmaf(d2, L2E, ch.z));
        o.w = os2 * FAST_EXP2(fmaf(d3, L2E, ch.w));
        // 64 lanes x 16 B = 1 KB contiguous store per wave per row
        *reinterpret_cast<float4*>(obase + (size_t)row * N2) = o;
    }
}

extern "C" void kernel_launch(void* const* d_in, const int* in_sizes, int n_in,
                              void* d_out, int out_size, void* d_ws, size_t ws_size,
                              hipStream_t stream) {
    (void)in_sizes; (void)n_in; (void)d_ws; (void)ws_size; (void)out_size;
    const float* x1  = (const float*)d_in[0];
    const float* x2  = (const float*)d_in[1];
    const float* ls  = (const float*)d_in[2];
    const float* osc = (const float*)d_in[3];
    float* out = (float*)d_out;

    const int R = 4, N1 = 4096, N2 = 4096;
    dim3 grid(N2 / BJ, N1 / BI, R);
    rbf_kernel<<<grid, dim3(256), 0, stream>>>(x1, x2, ls, osc, out, N1, N2);
}

// Round 4
// 48.796 us; speedup vs baseline: 1.1281x; 1.0460x over previous
//
#include <hip/hip_runtime.h>

// RBF kernel matrix: out[r,i,j] = os^2 * exp(-0.5 * ||(x1_i - x2_j)/ls||^2)
// R=4, N1=N2=4096, D=8. Output 268 MB fp32 -> write-BW bound.
// fillBuffer proves 7.1 TB/s streaming-write => floor ~38 us.
// R3 = R2 with compile fixes: ext_vector float4 for nontemporal_store,
// __builtin_amdgcn_exp2f instead of __exp2f (glibc macro collision).

constexpr int D  = 8;
constexpr int BI = 32;    // x1 rows per block (8 per wave)
constexpr int BJ = 256;   // x2 cols per block (4 per lane)

typedef float vfloat4 __attribute__((ext_vector_type(4)));

#if __has_builtin(__builtin_amdgcn_exp2f)
#define FAST_EXP2(x) __builtin_amdgcn_exp2f(x)
#else
#define FAST_EXP2(x) __expf((x) * 0.69314718f)   // exp(x*ln2) == 2^x
#endif

__global__ __launch_bounds__(256, 6) void rbf_kernel(
    const float* __restrict__ x1, const float* __restrict__ x2,
    const float* __restrict__ ls, const float* __restrict__ osc,
    float* __restrict__ out, int N1, int N2)
{
    __shared__ float sb[D][BJ];   // x2 tile, scaled, d-major  (8 KB)
    __shared__ float sbb[BJ];     // ||b||^2 per j             (1 KB)
    __shared__ float sa[BI][D];   // x1 tile, scaled           (1 KB)
    __shared__ float sasq[BI];    // ||a||^2 per i             (128 B)

    const int r   = blockIdx.z;
    const int i0  = blockIdx.y * BI;
    const int j0  = blockIdx.x * BJ;
    const int tid = threadIdx.x;

    float4 l0 = *reinterpret_cast<const float4*>(ls);
    float4 l1 = *reinterpret_cast<const float4*>(ls + 4);
    float4 inv0, inv1;
    inv0.x = 1.0f / l0.x; inv0.y = 1.0f / l0.y; inv0.z = 1.0f / l0.z; inv0.w = 1.0f / l0.w;
    inv1.x = 1.0f / l1.x; inv1.y = 1.0f / l1.y; inv1.z = 1.0f / l1.z; inv1.w = 1.0f / l1.w;

    // ---- stage x2: one point per thread (wave reads 2 KB contiguous) ----
    {
        const float* src = x2 + ((size_t)r * N2 + j0 + tid) * D;
        float4 v0 = *reinterpret_cast<const float4*>(src);
        float4 v1 = *reinterpret_cast<const float4*>(src + 4);
        v0.x *= inv0.x; v0.y *= inv0.y; v0.z *= inv0.z; v0.w *= inv0.w;
        v1.x *= inv1.x; v1.y *= inv1.y; v1.z *= inv1.z; v1.w *= inv1.w;
        sb[0][tid] = v0.x; sb[1][tid] = v0.y; sb[2][tid] = v0.z; sb[3][tid] = v0.w;
        sb[4][tid] = v1.x; sb[5][tid] = v1.y; sb[6][tid] = v1.z; sb[7][tid] = v1.w;
        sbb[tid] = v0.x*v0.x + v0.y*v0.y + v0.z*v0.z + v0.w*v0.w
                 + v1.x*v1.x + v1.y*v1.y + v1.z*v1.z + v1.w*v1.w;
    }
    // ---- stage x1: threads 0..31, one point each ----
    if (tid < BI) {
        const float* src = x1 + ((size_t)r * N1 + i0 + tid) * D;
        float4 v0 = *reinterpret_cast<const float4*>(src);
        float4 v1 = *reinterpret_cast<const float4*>(src + 4);
        v0.x *= inv0.x; v0.y *= inv0.y; v0.z *= inv0.z; v0.w *= inv0.w;
        v1.x *= inv1.x; v1.y *= inv1.y; v1.z *= inv1.z; v1.w *= inv1.w;
        *reinterpret_cast<float4*>(&sa[tid][0]) = v0;
        *reinterpret_cast<float4*>(&sa[tid][4]) = v1;
        sasq[tid] = v0.x*v0.x + v0.y*v0.y + v0.z*v0.z + v0.w*v0.w
                  + v1.x*v1.x + v1.y*v1.y + v1.z*v1.z + v1.w*v1.w;
    }
    const float os2   = osc[0] * osc[0];
    const float lg2os = __log2f(os2);     // os2 * 2^t == 2^(t + lg2os); exact 0 for os=1
    __syncthreads();

    // ---- compute: wave wv owns rows wv*8..wv*8+7; lane owns 4 consecutive j ----
    const int lane = tid & 63;
    const int wv   = tid >> 6;

    float4 bd[D];                 // b values for this lane's 4 j, per dim
#pragma unroll
    for (int d = 0; d < D; ++d)
        bd[d] = *reinterpret_cast<const float4*>(&sb[d][lane * 4]);
    const float4 bb4 = *reinterpret_cast<const float4*>(&sbb[lane * 4]);

    constexpr float L2E  = 1.44269504f;   //  log2(e)
    constexpr float NH2E = -0.72134752f;  // -0.5*log2(e)

    float* obase = out + ((size_t)r * N1 + i0) * (size_t)N2 + j0 + lane * 4;

#pragma unroll
    for (int ii = 0; ii < 8; ++ii) {
        const int row = wv * 8 + ii;
        // wave-broadcast LDS reads (same address all lanes -> free)
        const float4 a0  = *reinterpret_cast<const float4*>(&sa[row][0]);
        const float4 a1  = *reinterpret_cast<const float4*>(&sa[row][4]);
        const float  asq = sasq[row];

        float4 ch;   // -0.5*log2e*(asq + bb_j) + log2(os^2)
        ch.x = fmaf(asq + bb4.x, NH2E, lg2os);
        ch.y = fmaf(asq + bb4.y, NH2E, lg2os);
        ch.z = fmaf(asq + bb4.z, NH2E, lg2os);
        ch.w = fmaf(asq + bb4.w, NH2E, lg2os);

        float d0 = 0.f, d1 = 0.f, d2 = 0.f, d3 = 0.f;
        const float a[D] = {a0.x, a0.y, a0.z, a0.w, a1.x, a1.y, a1.z, a1.w};
#pragma unroll
        for (int d = 0; d < D; ++d) {
            const float av = a[d];
            d0 = fmaf(av, bd[d].x, d0);
            d1 = fmaf(av, bd[d].y, d1);
            d2 = fmaf(av, bd[d].z, d2);
            d3 = fmaf(av, bd[d].w, d3);
        }
        // exp(-0.5*s)*os2 = 2^( dot*log2e - 0.5*log2e*(asq+bb) + log2os2 )
        vfloat4 o;
        o.x = FAST_EXP2(fmaf(d0, L2E, ch.x));
        o.y = FAST_EXP2(fmaf(d1, L2E, ch.y));
        o.z = FAST_EXP2(fmaf(d2, L2E, ch.z));
        o.w = FAST_EXP2(fmaf(d3, L2E, ch.w));
        // 64 lanes x 16 B = 1 KB contiguous nontemporal store per wave per row
        __builtin_nontemporal_store(o, reinterpret_cast<vfloat4*>(obase + (size_t)row * N2));
    }
}

extern "C" void kernel_launch(void* const* d_in, const int* in_sizes, int n_in,
                              void* d_out, int out_size, void* d_ws, size_t ws_size,
                              hipStream_t stream) {
    (void)in_sizes; (void)n_in; (void)d_ws; (void)ws_size; (void)out_size;
    const float* x1  = (const float*)d_in[0];
    const float* x2  = (const float*)d_in[1];
    const float* ls  = (const float*)d_in[2];
    const float* osc = (const float*)d_in[3];
    float* out = (float*)d_out;

    const int R = 4, N1 = 4096, N2 = 4096;
    dim3 grid(N2 / BJ, N1 / BI, R);
    rbf_kernel<<<grid, dim3(256), 0, stream>>>(x1, x2, ls, osc, out, N1, N2);
}

// Round 5
// 47.541 us; speedup vs baseline: 1.1579x; 1.0264x over previous
//
#include <hip/hip_runtime.h>

// RBF kernel matrix: out[r,i,j] = os^2 * exp(-0.5 * ||(x1_i - x2_j)/ls||^2)
// R=4, N1=N2=4096, D=8. Output 268 MB fp32 -> write-BW bound.
// fillBuffer (plain stores) proves 7.1 TB/s streaming-write => floor ~38 us.
// R4: plain stores (drop nontemporal), BJ=512 so each wave writes 2 KB
// contiguous per row-visit (two adjacent dwordx4), launch_bounds(256,4).

constexpr int D  = 8;
constexpr int BI = 32;    // x1 rows per block (8 per wave)
constexpr int BJ = 512;   // x2 cols per block (2 chunks of 4 per lane)

#if __has_builtin(__builtin_amdgcn_exp2f)
#define FAST_EXP2(x) __builtin_amdgcn_exp2f(x)
#else
#define FAST_EXP2(x) __expf((x) * 0.69314718f)   // exp(x*ln2) == 2^x
#endif

__global__ __launch_bounds__(256, 4) void rbf_kernel(
    const float* __restrict__ x1, const float* __restrict__ x2,
    const float* __restrict__ ls, const float* __restrict__ osc,
    float* __restrict__ out, int N1, int N2)
{
    __shared__ float sb[D][BJ];   // x2 tile, scaled, d-major  (16 KB)
    __shared__ float sbb[BJ];     // ||b||^2 per j             (2 KB)
    __shared__ float sa[BI][D];   // x1 tile, scaled           (1 KB)
    __shared__ float sasq[BI];    // ||a||^2 per i             (128 B)

    const int r   = blockIdx.z;
    const int i0  = blockIdx.y * BI;
    const int j0  = blockIdx.x * BJ;
    const int tid = threadIdx.x;

    float4 l0 = *reinterpret_cast<const float4*>(ls);
    float4 l1 = *reinterpret_cast<const float4*>(ls + 4);
    float4 inv0, inv1;
    inv0.x = 1.0f / l0.x; inv0.y = 1.0f / l0.y; inv0.z = 1.0f / l0.z; inv0.w = 1.0f / l0.w;
    inv1.x = 1.0f / l1.x; inv1.y = 1.0f / l1.y; inv1.z = 1.0f / l1.z; inv1.w = 1.0f / l1.w;

    // ---- stage x2: 2 points per thread (wave reads 2 KB contiguous per pass) ----
#pragma unroll
    for (int k = 0; k < 2; ++k) {
        const int p = k * 256 + tid;
        const float* src = x2 + ((size_t)r * N2 + j0 + p) * D;
        float4 v0 = *reinterpret_cast<const float4*>(src);
        float4 v1 = *reinterpret_cast<const float4*>(src + 4);
        v0.x *= inv0.x; v0.y *= inv0.y; v0.z *= inv0.z; v0.w *= inv0.w;
        v1.x *= inv1.x; v1.y *= inv1.y; v1.z *= inv1.z; v1.w *= inv1.w;
        sb[0][p] = v0.x; sb[1][p] = v0.y; sb[2][p] = v0.z; sb[3][p] = v0.w;
        sb[4][p] = v1.x; sb[5][p] = v1.y; sb[6][p] = v1.z; sb[7][p] = v1.w;
        sbb[p] = v0.x*v0.x + v0.y*v0.y + v0.z*v0.z + v0.w*v0.w
               + v1.x*v1.x + v1.y*v1.y + v1.z*v1.z + v1.w*v1.w;
    }
    // ---- stage x1: threads 0..31, one point each ----
    if (tid < BI) {
        const float* src = x1 + ((size_t)r * N1 + i0 + tid) * D;
        float4 v0 = *reinterpret_cast<const float4*>(src);
        float4 v1 = *reinterpret_cast<const float4*>(src + 4);
        v0.x *= inv0.x; v0.y *= inv0.y; v0.z *= inv0.z; v0.w *= inv0.w;
        v1.x *= inv1.x; v1.y *= inv1.y; v1.z *= inv1.z; v1.w *= inv1.w;
        *reinterpret_cast<float4*>(&sa[tid][0]) = v0;
        *reinterpret_cast<float4*>(&sa[tid][4]) = v1;
        sasq[tid] = v0.x*v0.x + v0.y*v0.y + v0.z*v0.z + v0.w*v0.w
                  + v1.x*v1.x + v1.y*v1.y + v1.z*v1.z + v1.w*v1.w;
    }
    const float os2   = osc[0] * osc[0];
    const float lg2os = __log2f(os2);     // os2*2^t == 2^(t+lg2os); exact 0 for os=1
    __syncthreads();

    // ---- compute: wave wv owns rows wv*8..wv*8+7; lane owns j={lane*4, 256+lane*4} ----
    const int lane = tid & 63;
    const int wv   = tid >> 6;

    float4 bd0[D], bd1[D];        // b values for this lane's two j-chunks, per dim
#pragma unroll
    for (int d = 0; d < D; ++d) {
        bd0[d] = *reinterpret_cast<const float4*>(&sb[d][lane * 4]);
        bd1[d] = *reinterpret_cast<const float4*>(&sb[d][256 + lane * 4]);
    }
    const float4 bbA = *reinterpret_cast<const float4*>(&sbb[lane * 4]);
    const float4 bbB = *reinterpret_cast<const float4*>(&sbb[256 + lane * 4]);

    constexpr float L2E  = 1.44269504f;   //  log2(e)
    constexpr float NH2E = -0.72134752f;  // -0.5*log2(e)

    // per-lane constants: cb = -0.5*log2e*bb + log2(os^2)
    float4 cb0, cb1;
    cb0.x = fmaf(bbA.x, NH2E, lg2os); cb0.y = fmaf(bbA.y, NH2E, lg2os);
    cb0.z = fmaf(bbA.z, NH2E, lg2os); cb0.w = fmaf(bbA.w, NH2E, lg2os);
    cb1.x = fmaf(bbB.x, NH2E, lg2os); cb1.y = fmaf(bbB.y, NH2E, lg2os);
    cb1.z = fmaf(bbB.z, NH2E, lg2os); cb1.w = fmaf(bbB.w, NH2E, lg2os);

    float* obase = out + ((size_t)r * N1 + i0) * (size_t)N2 + j0 + lane * 4;

#pragma unroll
    for (int ii = 0; ii < 8; ++ii) {
        const int row = wv * 8 + ii;
        // wave-broadcast LDS reads (same address all lanes -> free)
        const float4 a0  = *reinterpret_cast<const float4*>(&sa[row][0]);
        const float4 a1  = *reinterpret_cast<const float4*>(&sa[row][4]);
        const float  ca  = sasq[row] * NH2E;   // row term

        float p0 = 0.f, p1 = 0.f, p2 = 0.f, p3 = 0.f;
        float q0 = 0.f, q1 = 0.f, q2 = 0.f, q3 = 0.f;
        const float a[D] = {a0.x, a0.y, a0.z, a0.w, a1.x, a1.y, a1.z, a1.w};
#pragma unroll
        for (int d = 0; d < D; ++d) {
            const float av = a[d];
            p0 = fmaf(av, bd0[d].x, p0);
            p1 = fmaf(av, bd0[d].y, p1);
            p2 = fmaf(av, bd0[d].z, p2);
            p3 = fmaf(av, bd0[d].w, p3);
            q0 = fmaf(av, bd1[d].x, q0);
            q1 = fmaf(av, bd1[d].y, q1);
            q2 = fmaf(av, bd1[d].z, q2);
            q3 = fmaf(av, bd1[d].w, q3);
        }
        // exp(-0.5*s)*os2 = 2^( dot*log2e + ca + cb )
        float4 oA, oB;
        oA.x = FAST_EXP2(fmaf(p0, L2E, ca + cb0.x));
        oA.y = FAST_EXP2(fmaf(p1, L2E, ca + cb0.y));
        oA.z = FAST_EXP2(fmaf(p2, L2E, ca + cb0.z));
        oA.w = FAST_EXP2(fmaf(p3, L2E, ca + cb0.w));
        oB.x = FAST_EXP2(fmaf(q0, L2E, ca + cb1.x));
        oB.y = FAST_EXP2(fmaf(q1, L2E, ca + cb1.y));
        oB.z = FAST_EXP2(fmaf(q2, L2E, ca + cb1.z));
        oB.w = FAST_EXP2(fmaf(q3, L2E, ca + cb1.w));
        // two adjacent 1 KB wave-stores -> 2 KB contiguous run per row-visit
        float* op = obase + (size_t)row * N2;
        *reinterpret_cast<float4*>(op)       = oA;
        *reinterpret_cast<float4*>(op + 256) = oB;
    }
}

extern "C" void kernel_launch(void* const* d_in, const int* in_sizes, int n_in,
                              void* d_out, int out_size, void* d_ws, size_t ws_size,
                              hipStream_t stream) {
    (void)in_sizes; (void)n_in; (void)d_ws; (void)ws_size; (void)out_size;
    const float* x1  = (const float*)d_in[0];
    const float* x2  = (const float*)d_in[1];
    const float* ls  = (const float*)d_in[2];
    const float* osc = (const float*)d_in[3];
    float* out = (float*)d_out;

    const int R = 4, N1 = 4096, N2 = 4096;
    dim3 grid(N2 / BJ, N1 / BI, R);
    rbf_kernel<<<grid, dim3(256), 0, stream>>>(x1, x2, ls, osc, out, N1, N2);
}

// Round 6
// 47.327 us; speedup vs baseline: 1.1631x; 1.0045x over previous
//
#include <hip/hip_runtime.h>

// RBF kernel matrix: out[r,i,j] = os^2 * exp(-0.5 * ||(x1_i - x2_j)/ls||^2)
// R=4, N1=N2=4096, D=8. Output 268 MB fp32 -> write-BW bound.
// fillBuffer (plain stores) proves 7.1 TB/s streaming-write => floor ~38 us.
// R5: amortize staging — stage x2 tile ONCE per block, then loop 4 i-subtiles
// (128 rows, 256 KB output per block). x1 rows read as wave-uniform global
// loads (s_load, L2-resident) — no LDS/barrier in the steady loop, so the
// store stream is near-continuous.

constexpr int D  = 8;
constexpr int BI = 32;    // rows per i-subtile (8 per wave)
constexpr int IT = 4;     // i-subtiles per block -> 128 rows/block
constexpr int BJ = 512;   // x2 cols per block (2 chunks of 4 per lane)

#if __has_builtin(__builtin_amdgcn_exp2f)
#define FAST_EXP2(x) __builtin_amdgcn_exp2f(x)
#else
#define FAST_EXP2(x) __expf((x) * 0.69314718f)   // exp(x*ln2) == 2^x
#endif

__global__ __launch_bounds__(256, 4) void rbf_kernel(
    const float* __restrict__ x1, const float* __restrict__ x2,
    const float* __restrict__ ls, const float* __restrict__ osc,
    float* __restrict__ out, int N1, int N2)
{
    __shared__ float sb[D][BJ];   // x2 tile, scaled, d-major  (16 KB)
    __shared__ float sbb[BJ];     // ||b||^2 per j             (2 KB)

    const int r   = blockIdx.z;
    const int i0  = blockIdx.y * (BI * IT);
    const int j0  = blockIdx.x * BJ;
    const int tid = threadIdx.x;

    float4 l0 = *reinterpret_cast<const float4*>(ls);
    float4 l1 = *reinterpret_cast<const float4*>(ls + 4);
    float4 inv0, inv1;
    inv0.x = 1.0f / l0.x; inv0.y = 1.0f / l0.y; inv0.z = 1.0f / l0.z; inv0.w = 1.0f / l0.w;
    inv1.x = 1.0f / l1.x; inv1.y = 1.0f / l1.y; inv1.z = 1.0f / l1.z; inv1.w = 1.0f / l1.w;

    // ---- stage x2: 2 points per thread (wave reads 2 KB contiguous per pass) ----
#pragma unroll
    for (int k = 0; k < 2; ++k) {
        const int p = k * 256 + tid;
        const float* src = x2 + ((size_t)r * N2 + j0 + p) * D;
        float4 v0 = *reinterpret_cast<const float4*>(src);
        float4 v1 = *reinterpret_cast<const float4*>(src + 4);
        v0.x *= inv0.x; v0.y *= inv0.y; v0.z *= inv0.z; v0.w *= inv0.w;
        v1.x *= inv1.x; v1.y *= inv1.y; v1.z *= inv1.z; v1.w *= inv1.w;
        sb[0][p] = v0.x; sb[1][p] = v0.y; sb[2][p] = v0.z; sb[3][p] = v0.w;
        sb[4][p] = v1.x; sb[5][p] = v1.y; sb[6][p] = v1.z; sb[7][p] = v1.w;
        sbb[p] = v0.x*v0.x + v0.y*v0.y + v0.z*v0.z + v0.w*v0.w
               + v1.x*v1.x + v1.y*v1.y + v1.z*v1.z + v1.w*v1.w;
    }
    const float os2   = osc[0] * osc[0];
    const float lg2os = __log2f(os2);     // os2*2^t == 2^(t+lg2os); exact 0 for os=1
    __syncthreads();                      // the ONLY barrier in the kernel

    // ---- per-lane j-state (register-resident for the whole block) ----
    const int lane = tid & 63;
    const int wv   = tid >> 6;

    float4 bd0[D], bd1[D];
#pragma unroll
    for (int d = 0; d < D; ++d) {
        bd0[d] = *reinterpret_cast<const float4*>(&sb[d][lane * 4]);
        bd1[d] = *reinterpret_cast<const float4*>(&sb[d][256 + lane * 4]);
    }
    const float4 bbA = *reinterpret_cast<const float4*>(&sbb[lane * 4]);
    const float4 bbB = *reinterpret_cast<const float4*>(&sbb[256 + lane * 4]);

    constexpr float L2E  = 1.44269504f;   //  log2(e)
    constexpr float NH2E = -0.72134752f;  // -0.5*log2(e)

    float4 cb0, cb1;   // -0.5*log2e*bb + log2(os^2)
    cb0.x = fmaf(bbA.x, NH2E, lg2os); cb0.y = fmaf(bbA.y, NH2E, lg2os);
    cb0.z = fmaf(bbA.z, NH2E, lg2os); cb0.w = fmaf(bbA.w, NH2E, lg2os);
    cb1.x = fmaf(bbB.x, NH2E, lg2os); cb1.y = fmaf(bbB.y, NH2E, lg2os);
    cb1.z = fmaf(bbB.z, NH2E, lg2os); cb1.w = fmaf(bbB.w, NH2E, lg2os);

    float* obase = out + ((size_t)r * N1 + i0) * (size_t)N2 + j0 + lane * 4;
    const float* x1base = x1 + ((size_t)r * N1 + i0) * D;

    // ---- steady loop: 32 rows per wave, no barriers, uniform x1 loads ----
#pragma unroll 4
    for (int t = 0; t < IT; ++t) {
#pragma unroll
        for (int ii = 0; ii < 8; ++ii) {
            const int row = t * BI + wv * 8 + ii;
            // wave-uniform address -> scalar loads from L2-resident x1
            const float* xp = x1base + (size_t)row * D;
            float a[D];
            float asq = 0.f;
            {
                const float4 u0 = *reinterpret_cast<const float4*>(xp);
                const float4 u1 = *reinterpret_cast<const float4*>(xp + 4);
                a[0] = u0.x * inv0.x; a[1] = u0.y * inv0.y;
                a[2] = u0.z * inv0.z; a[3] = u0.w * inv0.w;
                a[4] = u1.x * inv1.x; a[5] = u1.y * inv1.y;
                a[6] = u1.z * inv1.z; a[7] = u1.w * inv1.w;
#pragma unroll
                for (int d = 0; d < D; ++d) asq = fmaf(a[d], a[d], asq);
            }
            const float ca = asq * NH2E;

            float p0 = 0.f, p1 = 0.f, p2 = 0.f, p3 = 0.f;
            float q0 = 0.f, q1 = 0.f, q2 = 0.f, q3 = 0.f;
#pragma unroll
            for (int d = 0; d < D; ++d) {
                const float av = a[d];
                p0 = fmaf(av, bd0[d].x, p0);
                p1 = fmaf(av, bd0[d].y, p1);
                p2 = fmaf(av, bd0[d].z, p2);
                p3 = fmaf(av, bd0[d].w, p3);
                q0 = fmaf(av, bd1[d].x, q0);
                q1 = fmaf(av, bd1[d].y, q1);
                q2 = fmaf(av, bd1[d].z, q2);
                q3 = fmaf(av, bd1[d].w, q3);
            }
            float4 oA, oB;
            oA.x = FAST_EXP2(fmaf(p0, L2E, ca + cb0.x));
            oA.y = FAST_EXP2(fmaf(p1, L2E, ca + cb0.y));
            oA.z = FAST_EXP2(fmaf(p2, L2E, ca + cb0.z));
            oA.w = FAST_EXP2(fmaf(p3, L2E, ca + cb0.w));
            oB.x = FAST_EXP2(fmaf(q0, L2E, ca + cb1.x));
            oB.y = FAST_EXP2(fmaf(q1, L2E, ca + cb1.y));
            oB.z = FAST_EXP2(fmaf(q2, L2E, ca + cb1.z));
            oB.w = FAST_EXP2(fmaf(q3, L2E, ca + cb1.w));
            float* op = obase + (size_t)row * N2;
            *reinterpret_cast<float4*>(op)       = oA;
            *reinterpret_cast<float4*>(op + 256) = oB;
        }
    }
}

extern "C" void kernel_launch(void* const* d_in, const int* in_sizes, int n_in,
                              void* d_out, int out_size, void* d_ws, size_t ws_size,
                              hipStream_t stream) {
    (void)in_sizes; (void)n_in; (void)d_ws; (void)ws_size; (void)out_size;
    const float* x1  = (const float*)d_in[0];
    const float* x2  = (const float*)d_in[1];
    const float* ls  = (const float*)d_in[2];
    const float* osc = (const float*)d_in[3];
    float* out = (float*)d_out;

    const int R = 4, N1 = 4096, N2 = 4096;
    dim3 grid(N2 / BJ, N1 / (BI * IT), R);
    rbf_kernel<<<grid, dim3(256), 0, stream>>>(x1, x2, ls, osc, out, N1, N2);
}